// Round 1
// baseline (8135.169 us; speedup 1.0000x reference)
//
#include <hip/hip_runtime.h>
#include <hip/hip_bf16.h>

#define B_SZ  64
#define S_LEN 512
#define I_DIM 1024
#define H_DIM 1024

typedef __bf16 bf16x8 __attribute__((ext_vector_type(8)));
typedef float  f32x4  __attribute__((ext_vector_type(4)));

#define MFMA16(a,b,c) __builtin_amdgcn_mfma_f32_16x16x32_bf16((a),(b),(c),0,0,0)

__device__ inline bf16x8 cvt8(const float4& a, const float4& b) {
  bf16x8 v;
  v[0]=(__bf16)a.x; v[1]=(__bf16)a.y; v[2]=(__bf16)a.z; v[3]=(__bf16)a.w;
  v[4]=(__bf16)b.x; v[5]=(__bf16)b.y; v[6]=(__bf16)b.z; v[7]=(__bf16)b.w;
  return v;
}

// ------------- phase 0: hidden_state (fp32) -> hbuf[0] (bf16) -------------
__global__ void k_hinit(const float* __restrict__ h0, __bf16* __restrict__ hbuf) {
  const int i = blockIdx.x * 256 + threadIdx.x;      // 16384 threads x 4 elems
  const float4 v = ((const float4*)h0)[i];
  __bf16* p = hbuf + (size_t)i * 4;
  p[0] = (__bf16)v.x; p[1] = (__bf16)v.y; p[2] = (__bf16)v.z; p[3] = (__bf16)v.w;
}

// ------------- phase 1: x_proj = seq @ w_ih^T + b_ih  -> d_out -------------
// 128x128 tile, BK=32, 4 waves each 64x64 (4x4 frags of 16x16x32 bf16 MFMA).
// LDS rows padded to 40 bf16 (80 B): 16-B aligned b128 reads, banks 20r%32
// -> only (r, r+8) alias = 2-way = free.
#define P1_LDA 40
__global__ __launch_bounds__(256, 2) void k_xproj(
    const float* __restrict__ A,     // [M][K] sequence (M = B*S)
    const float* __restrict__ W,     // [N][K] w_ih
    const float* __restrict__ bias,  // [N]
    float* __restrict__ C)           // [M][N]
{
  constexpr int K = I_DIM, N = H_DIM;
  __shared__ __bf16 As[128][P1_LDA];
  __shared__ __bf16 Bs[128][P1_LDA];
  const int bid = blockIdx.x;
  const int nt = bid & 7, mt = bid >> 3;   // nt fastest -> A-panel L2 reuse
  const int m0 = mt * 128, n0 = nt * 128;
  const int tid = threadIdx.x, lane = tid & 63, wv = tid >> 6;
  const int wm = (wv & 1) * 64, wn = (wv >> 1) * 64;
  const int fr = lane & 15, fq = lane >> 4;
  const int srow = tid >> 1, scol = (tid & 1) * 16;
  const float* gA = A + (size_t)(m0 + srow) * K + scol;
  const float* gB = W + (size_t)(n0 + srow) * K + scol;
  const f32x4 zero = {0.f, 0.f, 0.f, 0.f};
  f32x4 acc[4][4];
  #pragma unroll
  for (int m = 0; m < 4; ++m)
    #pragma unroll
    for (int n = 0; n < 4; ++n) acc[m][n] = zero;

  for (int k0 = 0; k0 < K; k0 += 32) {
    float4 a0 = *(const float4*)(gA + k0);
    float4 a1 = *(const float4*)(gA + k0 + 4);
    float4 a2 = *(const float4*)(gA + k0 + 8);
    float4 a3 = *(const float4*)(gA + k0 + 12);
    float4 b0 = *(const float4*)(gB + k0);
    float4 b1 = *(const float4*)(gB + k0 + 4);
    float4 b2 = *(const float4*)(gB + k0 + 8);
    float4 b3 = *(const float4*)(gB + k0 + 12);
    __syncthreads();
    *(bf16x8*)(&As[srow][scol])     = cvt8(a0, a1);
    *(bf16x8*)(&As[srow][scol + 8]) = cvt8(a2, a3);
    *(bf16x8*)(&Bs[srow][scol])     = cvt8(b0, b1);
    *(bf16x8*)(&Bs[srow][scol + 8]) = cvt8(b2, b3);
    __syncthreads();
    bf16x8 af[4], bfr[4];
    #pragma unroll
    for (int m = 0; m < 4; ++m) af[m]  = *(const bf16x8*)(&As[wm + m*16 + fr][fq*8]);
    #pragma unroll
    for (int n = 0; n < 4; ++n) bfr[n] = *(const bf16x8*)(&Bs[wn + n*16 + fr][fq*8]);
    #pragma unroll
    for (int m = 0; m < 4; ++m)
      #pragma unroll
      for (int n = 0; n < 4; ++n)
        acc[m][n] = MFMA16(af[m], bfr[n], acc[m][n]);
  }
  // epilogue: D col = lane&15, row = (lane>>4)*4 + j  (verified m89/m91 layout)
  #pragma unroll
  for (int n = 0; n < 4; ++n) {
    const int col = n0 + wn + n*16 + fr;
    const float bv = bias[col];
    #pragma unroll
    for (int m = 0; m < 4; ++m) {
      const int row = m0 + wm + m*16 + fq*4;
      #pragma unroll
      for (int jj = 0; jj < 4; ++jj)
        C[(size_t)(row + jj) * N + col] = acc[m][n][jj] + bv;
    }
  }
}

// ------------- phase 2: persistent recurrence -------------
// 4 groups x 16 batches; 32 WGs/group, each owns 32 rows of w_hh in LDS
// (bf16, XOR-swizzled: elem [r][k ^ ((r&7)<<3)] -> 2-way bank alias = free).
// h ping-pongs in hbuf[2][B][H] (bf16, ws). Per-step per-group barrier via
// monotone atomic counter (agent scope, release/acquire for cross-XCD vis).
#define NGR 4
#define BG  16
#define WPG 32
#define RPW 32

__global__ __launch_bounds__(128, 1) void k_rnn(
    const float* __restrict__ w_hh, const float* __restrict__ b_hh,
    float* __restrict__ out, __bf16* __restrict__ hbuf,
    unsigned* __restrict__ ctrs)
{
  __shared__ __bf16 Ws[RPW][H_DIM];            // 64 KB
  const int bid = blockIdx.x;
  const int g = bid >> 5;                      // group (batches g*16..+16)
  const int j = bid & 31;                      // WG within group
  const int r0 = j * RPW;                      // owned output rows
  const int tid = threadIdx.x, lane = tid & 63, wv = tid >> 6;

  // stage W slice once: 32 rows x 1024 fp32 -> bf16 swizzled LDS
  for (int idx = tid * 8; idx < RPW * H_DIM; idx += 128 * 8) {
    const int r = idx >> 10, k = idx & 1023;
    const float* src = w_hh + (size_t)(r0 + r) * H_DIM + k;
    float4 w0 = *(const float4*)(src);
    float4 w1 = *(const float4*)(src + 4);
    *(bf16x8*)(&Ws[r][k ^ ((r & 7) << 3)]) = cvt8(w0, w1);
  }
  __syncthreads();

  const int fr = lane & 15, fq = lane >> 4;
  const int lrow = wv * 16 + fr;               // local W row (0..31)
  const int myrow = r0 + lrow;                 // hidden index this lane outputs
  const float bh = b_hh[myrow];
  const int bl0 = fq * 4;                      // local batch base for D rows
  const int swz = (lrow & 7) << 3;
  unsigned* ctr = ctrs + (g << 6);             // 256 B apart per group
  const size_t bsh = (size_t)B_SZ * S_LEN * H_DIM;
  const size_t BH = (size_t)B_SZ * H_DIM;
  // A-frag base: lane holds h[batch = g*16 + fr][k = fq*8 + i]
  const __bf16* hrd0 = hbuf + (size_t)(g * BG + fr) * H_DIM + fq * 8;
  const __bf16* hrd1 = hrd0 + BH;
  __bf16* hw0 = hbuf + BH;                     // write target when rd==0
  __bf16* hw1 = hbuf;

  for (int t = 0; t < S_LEN; ++t) {
    const int rd = t & 1;
    // prefetch x_t (lives in d_out, written by phase 1; we own these cells)
    float xv[4]; size_t xoff[4];
    #pragma unroll
    for (int jj = 0; jj < 4; ++jj) {
      const int b = g * BG + bl0 + jj;
      xoff[jj] = ((size_t)b * S_LEN + t) * H_DIM + myrow;
      xv[jj] = out[xoff[jj]];
    }
    const __bf16* hb = rd ? hrd1 : hrd0;
    const f32x4 z = {0.f, 0.f, 0.f, 0.f};
    f32x4 acc0 = z, acc1 = z;                  // 2 chains to hide MFMA latency
    #pragma unroll 4
    for (int kk = 0; kk < 32; kk += 2) {
      bf16x8 a0 = *(const bf16x8*)(hb + kk * 32);
      bf16x8 w0 = *(const bf16x8*)(&Ws[lrow][(kk * 32 + fq * 8) ^ swz]);
      acc0 = MFMA16(a0, w0, acc0);
      bf16x8 a1 = *(const bf16x8*)(hb + (kk + 1) * 32);
      bf16x8 w1 = *(const bf16x8*)(&Ws[lrow][((kk + 1) * 32 + fq * 8) ^ swz]);
      acc1 = MFMA16(a1, w1, acc1);
    }
    __bf16* hw = rd ? hw1 : hw0;
    #pragma unroll
    for (int jj = 0; jj < 4; ++jj) {
      const int b = g * BG + bl0 + jj;
      float v = xv[jj] + acc0[jj] + acc1[jj] + bh;
      v = fmaxf(v, 0.f);
      out[xoff[jj]] = v;                       // overwrite x_t with h_t
      hw[(size_t)b * H_DIM + myrow] = (__bf16)v;
      if (t == S_LEN - 1) out[bsh + (size_t)b * H_DIM + myrow] = v;  // h_last
    }
    // ---- per-group barrier (monotone counter, no reset -> no ABA) ----
    __threadfence();                           // release our h writes
    __syncthreads();
    if (tid == 0) {
      __hip_atomic_fetch_add(ctr, 1u, __ATOMIC_RELEASE, __HIP_MEMORY_SCOPE_AGENT);
      const unsigned tgt = (unsigned)(t + 1) * WPG;
      while (__hip_atomic_load(ctr, __ATOMIC_ACQUIRE, __HIP_MEMORY_SCOPE_AGENT) < tgt)
        __builtin_amdgcn_s_sleep(8);
    }
    __syncthreads();
    __threadfence();                           // acquire: invalidate stale h
  }
}

extern "C" void kernel_launch(void* const* d_in, const int* in_sizes, int n_in,
                              void* d_out, int out_size, void* d_ws, size_t ws_size,
                              hipStream_t stream) {
  const float* seq  = (const float*)d_in[0];
  const float* h0   = (const float*)d_in[1];
  const float* w_ih = (const float*)d_in[2];
  const float* w_hh = (const float*)d_in[3];
  const float* b_ih = (const float*)d_in[4];
  const float* b_hh = (const float*)d_in[5];
  float* out = (float*)d_out;

  __bf16* hbuf = (__bf16*)d_ws;                                  // [2][B][H] bf16
  unsigned* ctrs = (unsigned*)((char*)d_ws + (size_t)2 * B_SZ * H_DIM * sizeof(__bf16));

  hipMemsetAsync(ctrs, 0, NGR * 64 * sizeof(unsigned), stream);
  k_hinit<<<dim3(B_SZ * H_DIM / 4 / 256), dim3(256), 0, stream>>>(h0, hbuf);
  k_xproj<<<dim3((B_SZ * S_LEN / 128) * (H_DIM / 128)), dim3(256), 0, stream>>>(
      seq, w_ih, b_ih, out);

  const float* a0 = w_hh; const float* a1 = b_hh; float* a2 = out;
  __bf16* a3 = hbuf; unsigned* a4 = ctrs;
  void* args[5] = { &a0, &a1, &a2, &a3, &a4 };
  hipLaunchCooperativeKernel((void*)k_rnn, dim3(NGR * WPG), dim3(128),
                             args, 0, stream);
}

// Round 2
// 1659.958 us; speedup vs baseline: 4.9008x; 4.9008x over previous
//
#include <hip/hip_runtime.h>
#include <hip/hip_bf16.h>

#define B_SZ  64
#define S_LEN 512
#define I_DIM 1024
#define H_DIM 1024

typedef __bf16 bf16x8 __attribute__((ext_vector_type(8)));
typedef __bf16 bf16x4 __attribute__((ext_vector_type(4)));
typedef float  f32x4  __attribute__((ext_vector_type(4)));
typedef unsigned u32x4 __attribute__((ext_vector_type(4)));

#define MFMA16(a,b,c) __builtin_amdgcn_mfma_f32_16x16x32_bf16((a),(b),(c),0,0,0)

__device__ inline bf16x8 cvt8(const float4& a, const float4& b) {
  bf16x8 v;
  v[0]=(__bf16)a.x; v[1]=(__bf16)a.y; v[2]=(__bf16)a.z; v[3]=(__bf16)a.w;
  v[4]=(__bf16)b.x; v[5]=(__bf16)b.y; v[6]=(__bf16)b.z; v[7]=(__bf16)b.w;
  return v;
}
__device__ inline bf16x8 cvt8v(const f32x4& a, const f32x4& b) {
  bf16x8 v;
  v[0]=(__bf16)a[0]; v[1]=(__bf16)a[1]; v[2]=(__bf16)a[2]; v[3]=(__bf16)a[3];
  v[4]=(__bf16)b[0]; v[5]=(__bf16)b[1]; v[6]=(__bf16)b[2]; v[7]=(__bf16)b[3];
  return v;
}

// ---- LLC-coherent (bypass L1/L2) access helpers: cross-XCD data plane ----
__device__ inline u32x4 load_b128_sc(const void* p) {
  u32x4 r;
  asm volatile("global_load_dwordx4 %0, %1, off sc0 sc1"
               : "=v"(r) : "v"(p) : "memory");
  return r;
}
__device__ inline void store_b64_sc(void* p, unsigned long long v) {
  asm volatile("global_store_dwordx2 %0, %1, off sc0 sc1"
               :: "v"(p), "v"(v) : "memory");
}
__device__ inline f32x4 load_b128_pf(const void* p) {   // normal cached load
  f32x4 r;
  asm volatile("global_load_dwordx4 %0, %1, off"
               : "=v"(r) : "v"(p) : "memory");
  return r;
}
__device__ inline void waitcnt_vm0() { asm volatile("s_waitcnt vmcnt(0)" ::: "memory"); }

// ------------- phase 0: hidden_state (fp32) -> hbuf[0] (bf16) -------------
__global__ void k_hinit(const float* __restrict__ h0, __bf16* __restrict__ hbuf) {
  const int i = blockIdx.x * 256 + threadIdx.x;
  const float4 v = ((const float4*)h0)[i];
  __bf16* p = hbuf + (size_t)i * 4;
  p[0] = (__bf16)v.x; p[1] = (__bf16)v.y; p[2] = (__bf16)v.z; p[3] = (__bf16)v.w;
}

// ------------- phase 1: x_proj = seq @ w_ih^T + b_ih  -> d_out -------------
#define P1_LDA 40
__global__ __launch_bounds__(256, 2) void k_xproj(
    const float* __restrict__ A, const float* __restrict__ W,
    const float* __restrict__ bias, float* __restrict__ C) {
  constexpr int K = I_DIM, N = H_DIM;
  __shared__ __bf16 As[128][P1_LDA];
  __shared__ __bf16 Bs[128][P1_LDA];
  const int bid = blockIdx.x;
  const int nt = bid & 7, mt = bid >> 3;
  const int m0 = mt * 128, n0 = nt * 128;
  const int tid = threadIdx.x, lane = tid & 63, wv = tid >> 6;
  const int wm = (wv & 1) * 64, wn = (wv >> 1) * 64;
  const int fr = lane & 15, fq = lane >> 4;
  const int srow = tid >> 1, scol = (tid & 1) * 16;
  const float* gA = A + (size_t)(m0 + srow) * K + scol;
  const float* gB = W + (size_t)(n0 + srow) * K + scol;
  const f32x4 zero = {0.f, 0.f, 0.f, 0.f};
  f32x4 acc[4][4];
  #pragma unroll
  for (int m = 0; m < 4; ++m)
    #pragma unroll
    for (int n = 0; n < 4; ++n) acc[m][n] = zero;

  for (int k0 = 0; k0 < K; k0 += 32) {
    float4 a0 = *(const float4*)(gA + k0);
    float4 a1 = *(const float4*)(gA + k0 + 4);
    float4 a2 = *(const float4*)(gA + k0 + 8);
    float4 a3 = *(const float4*)(gA + k0 + 12);
    float4 b0 = *(const float4*)(gB + k0);
    float4 b1 = *(const float4*)(gB + k0 + 4);
    float4 b2 = *(const float4*)(gB + k0 + 8);
    float4 b3 = *(const float4*)(gB + k0 + 12);
    __syncthreads();
    *(bf16x8*)(&As[srow][scol])     = cvt8(a0, a1);
    *(bf16x8*)(&As[srow][scol + 8]) = cvt8(a2, a3);
    *(bf16x8*)(&Bs[srow][scol])     = cvt8(b0, b1);
    *(bf16x8*)(&Bs[srow][scol + 8]) = cvt8(b2, b3);
    __syncthreads();
    bf16x8 af[4], bfr[4];
    #pragma unroll
    for (int m = 0; m < 4; ++m) af[m]  = *(const bf16x8*)(&As[wm + m*16 + fr][fq*8]);
    #pragma unroll
    for (int n = 0; n < 4; ++n) bfr[n] = *(const bf16x8*)(&Bs[wn + n*16 + fr][fq*8]);
    #pragma unroll
    for (int m = 0; m < 4; ++m)
      #pragma unroll
      for (int n = 0; n < 4; ++n)
        acc[m][n] = MFMA16(af[m], bfr[n], acc[m][n]);
  }
  #pragma unroll
  for (int n = 0; n < 4; ++n) {
    const int col = n0 + wn + n*16 + fr;
    const float bv = bias[col];
    #pragma unroll
    for (int m = 0; m < 4; ++m) {
      const int row = m0 + wm + m*16 + fq*4;
      #pragma unroll
      for (int jj = 0; jj < 4; ++jj)
        C[(size_t)(row + jj) * N + col] = acc[m][n][jj] + bv;
    }
  }
}

// ------------- phase 2: persistent recurrence -------------
// 4 groups x 16 batches. 16 WGs/group x 256 thr (4 waves); WG owns 64 rows.
// W_hh frags live in VGPRs (32 x bf16x8 = 128 VGPR/lane, loaded once).
// h ping-pongs through LLC (sc0 sc1 ops, no cache fences); per-step barrier =
// relaxed atomic counter after per-wave vmcnt(0) drain + syncthreads.
// MFMA: A=W (M=rows), B=h (N=batches) -> lane owns 4 consecutive out rows.
#define NGR 4
#define BG  16
#define WPG 16
#define RPW 64

__global__ __launch_bounds__(256, 1) void k_rnn(
    const float* __restrict__ w_hh, const float* __restrict__ b_hh,
    float* __restrict__ out, __bf16* __restrict__ hbuf,
    unsigned* __restrict__ ctrs)
{
  __shared__ __bf16 Hs[BG][H_DIM];               // 32 KB, XOR-swizzled
  const int bid = blockIdx.x;
  const int g = bid >> 4, j = bid & 15;
  const int r0 = j * RPW;
  const int tid = threadIdx.x, lane = tid & 63, wv = tid >> 6;
  const int fr = lane & 15, fq = lane >> 4;
  const int myW  = r0 + wv * 16 + fr;            // A-frag W row
  const int row4 = r0 + wv * 16 + fq * 4;        // D rows (4 consecutive)
  const int b    = g * BG + fr;                  // D batch (col)
  const int hswz = (fr & 7) << 3;

  // preload W fragments (loop-invariant): 32 x bf16x8 in VGPRs
  bf16x8 wfrag[32];
  {
    const float* wsrc = w_hh + (size_t)myW * H_DIM + fq * 8;
    #pragma unroll
    for (int kk = 0; kk < 32; ++kk) {
      f32x4 w0 = *(const f32x4*)(wsrc + kk * 32);
      f32x4 w1 = *(const f32x4*)(wsrc + kk * 32 + 4);
      wfrag[kk] = cvt8v(w0, w1);
    }
  }
  const f32x4 bh = *(const f32x4*)(b_hh + row4);
  unsigned* ctr = ctrs + (g << 6);
  const size_t BH  = (size_t)B_SZ * H_DIM;
  const size_t bsh = (size_t)B_SZ * S_LEN * H_DIM;
  const __bf16* hg0 = hbuf + (size_t)g * BG * H_DIM;   // group block, buf0

  size_t xo = (size_t)b * S_LEN * H_DIM + row4;
  f32x4 xv = load_b128_pf(out + xo);             // t=0 x prefetch

  for (int t = 0; t < S_LEN; ++t) {
    // ---- stage h_t: LLC -> LDS (coalesced sc1 loads, swizzled ds_write) ----
    const __bf16* hsrc = hg0 + (size_t)(t & 1) * BH;
    u32x4 st[8];
    #pragma unroll
    for (int i = 0; i < 8; ++i) {
      const int c = tid + (i << 8);              // 2048 x 16B chunks
      st[i] = load_b128_sc(hsrc + c * 8);
    }
    waitcnt_vm0();
    asm volatile("" : "+v"(xv));                 // pin: xv landed by now
    #pragma unroll
    for (int i = 0; i < 8; ++i) {
      const int c = tid + (i << 8);
      const int bb = c >> 7, k = (c & 127) << 3;
      *(u32x4*)&Hs[bb][k ^ ((bb & 7) << 3)] = st[i];
    }
    __syncthreads();

    // ---- MFMA: 32 x 16x16x32, 4 acc chains ----
    const f32x4 z = {0.f, 0.f, 0.f, 0.f};
    f32x4 a0 = z, a1 = z, a2 = z, a3 = z;
    #pragma unroll
    for (int kk = 0; kk < 32; kk += 4) {
      bf16x8 h0 = *(const bf16x8*)&Hs[fr][((kk + 0) * 32 + fq * 8) ^ hswz];
      a0 = MFMA16(wfrag[kk + 0], h0, a0);
      bf16x8 h1 = *(const bf16x8*)&Hs[fr][((kk + 1) * 32 + fq * 8) ^ hswz];
      a1 = MFMA16(wfrag[kk + 1], h1, a1);
      bf16x8 h2 = *(const bf16x8*)&Hs[fr][((kk + 2) * 32 + fq * 8) ^ hswz];
      a2 = MFMA16(wfrag[kk + 2], h2, a2);
      bf16x8 h3 = *(const bf16x8*)&Hs[fr][((kk + 3) * 32 + fq * 8) ^ hswz];
      a3 = MFMA16(wfrag[kk + 3], h3, a3);
    }

    // ---- epilogue: v = relu(x + hW^T + b); out (fp32), hbuf (bf16, sc1) ----
    f32x4 s = (a0 + a1) + (a2 + a3);
    f32x4 r;
    r[0] = fmaxf(xv[0] + s[0] + bh[0], 0.f);
    r[1] = fmaxf(xv[1] + s[1] + bh[1], 0.f);
    r[2] = fmaxf(xv[2] + s[2] + bh[2], 0.f);
    r[3] = fmaxf(xv[3] + s[3] + bh[3], 0.f);
    *(f32x4*)(out + xo) = r;                     // overwrite x_t with h_t
    if (t == S_LEN - 1)
      *(f32x4*)(out + bsh + (size_t)b * H_DIM + row4) = r;  // h_last
    bf16x4 hv;
    hv[0] = (__bf16)r[0]; hv[1] = (__bf16)r[1];
    hv[2] = (__bf16)r[2]; hv[3] = (__bf16)r[3];
    __bf16* hdst = hbuf + (size_t)((t + 1) & 1) * BH + (size_t)b * H_DIM + row4;
    store_b64_sc(hdst, __builtin_bit_cast(unsigned long long, hv));

    // ---- barrier: drain stores, arrive, prefetch x_{t+1}, poll ----
    waitcnt_vm0();                               // per-wave: h at LLC
    __syncthreads();                             // all waves drained
    if (tid == 0)
      __hip_atomic_fetch_add(ctr, 1u, __ATOMIC_RELAXED, __HIP_MEMORY_SCOPE_AGENT);
    xo += H_DIM;
    xv = load_b128_pf(out + xo);                 // overlaps with poll wait
    if (tid == 0) {
      const unsigned tgt = (unsigned)(t + 1) * WPG;
      while (__hip_atomic_load(ctr, __ATOMIC_RELAXED, __HIP_MEMORY_SCOPE_AGENT) < tgt)
        __builtin_amdgcn_s_sleep(1);
    }
    __syncthreads();
  }
}

extern "C" void kernel_launch(void* const* d_in, const int* in_sizes, int n_in,
                              void* d_out, int out_size, void* d_ws, size_t ws_size,
                              hipStream_t stream) {
  const float* seq  = (const float*)d_in[0];
  const float* h0   = (const float*)d_in[1];
  const float* w_ih = (const float*)d_in[2];
  const float* w_hh = (const float*)d_in[3];
  const float* b_ih = (const float*)d_in[4];
  const float* b_hh = (const float*)d_in[5];
  float* out = (float*)d_out;

  __bf16* hbuf = (__bf16*)d_ws;                  // [2][B][H] bf16
  unsigned* ctrs = (unsigned*)((char*)d_ws + (size_t)2 * B_SZ * H_DIM * sizeof(__bf16));

  hipMemsetAsync(ctrs, 0, NGR * 64 * sizeof(unsigned), stream);
  k_hinit<<<dim3(B_SZ * H_DIM / 4 / 256), dim3(256), 0, stream>>>(h0, hbuf);
  k_xproj<<<dim3((B_SZ * S_LEN / 128) * (H_DIM / 128)), dim3(256), 0, stream>>>(
      seq, w_ih, b_ih, out);

  const float* a0 = w_hh; const float* a1 = b_hh; float* a2 = out;
  __bf16* a3 = hbuf; unsigned* a4 = ctrs;
  void* args[5] = { &a0, &a1, &a2, &a3, &a4 };
  hipLaunchCooperativeKernel((void*)k_rnn, dim3(NGR * WPG), dim3(256),
                             args, 0, stream);
}